// Round 1
// 2265.980 us; speedup vs baseline: 1.8493x; 1.8493x over previous
//
#include <hip/hip_runtime.h>
#include <hip/hip_bf16.h>

// Problem constants
#define N1C   512
#define N2C   512
#define MC    1024
#define NOUTC 1024
#define WROWC 263168      // N1*N2 + N1 + N2
#define QOFFC 1024        // start of quadratic block in a W row
#define NPHASE 129        // phase 0: linear x/y; phases 1..128: 4 i-chunks each
#define NSPLIT 16         // split-K factor (j-windows)

typedef __attribute__((ext_vector_type(8))) short bf16x8;
typedef __attribute__((ext_vector_type(4))) float f32x4;

union FragU { bf16x8 v; __hip_bfloat162 h2[4]; };

__device__ __forceinline__ __hip_bfloat162 cvt2(float a, float b) {
    return __float22bfloat162_rn(make_float2(a, b));
}

// direct stage: load 8 fp32, convert, write bf16x8 to LDS (prologue only)
__device__ __forceinline__ void stage_direct(short* dst, const float* src) {
    f32x4 a = *(const f32x4*)src;
    f32x4 b = *(const f32x4*)(src + 4);
    FragU f;
    f.h2[0] = cvt2(a[0], a[1]); f.h2[1] = cvt2(a[2], a[3]);
    f.h2[2] = cvt2(b[0], b[1]); f.h2[3] = cvt2(b[2], b[3]);
    *(bf16x8*)dst = f.v;
}

// ---------------- x transpose: x[1024][512] -> xT[512][1024] ----------------
__global__ __launch_bounds__(256) void transpose_x(const float* __restrict__ x,
                                                   float* __restrict__ xT) {
    __shared__ float t[64][65];
    const int i0 = blockIdx.x * 64;     // i-tile (0..7)
    const int m0 = blockIdx.y * 64;     // m-tile (0..15)
    const int tx = threadIdx.x & 63;
    const int ty = threadIdx.x >> 6;
#pragma unroll
    for (int k = 0; k < 16; ++k)
        t[ty * 16 + k][tx] = x[(size_t)(m0 + ty * 16 + k) * N1C + i0 + tx];
    __syncthreads();
#pragma unroll
    for (int k = 0; k < 16; ++k)
        xT[(size_t)(i0 + ty * 16 + k) * MC + m0 + tx] = t[tx][ty * 16 + k];
}

// ---------------- split-K reduction: out = sum_j part[j] ----------------
__global__ __launch_bounds__(256) void reduce_parts(const float* __restrict__ part,
                                                    float* __restrict__ out) {
    const size_t idx = ((size_t)blockIdx.x * 256 + threadIdx.x) * 4;
    f32x4 s = *(const f32x4*)(part + idx);
#pragma unroll
    for (int j = 1; j < NSPLIT; ++j)
        s += *(const f32x4*)(part + (size_t)j * (MC * NOUTC) + idx);
    *(f32x4*)(out + idx) = s;
}

// ---------------- main kernel ----------------
template<bool USE_XT, bool USE_WS>
__global__ __launch_bounds__(256, 2) void quad_gemm(
        const float* __restrict__ x, const float* __restrict__ y,
        const float* __restrict__ W, const float* __restrict__ xT,
        float* __restrict__ out)   // USE_WS: partial base; else real out (atomics)
{
    // W tiles: [buf][ii][n-row][j + pad] : 2*4*64*40*2B = 40 KB
    __shared__ short sB[2][4][64][40];
    // x slice: [buf][ii][local row]      : 2*4*512*4B   = 16 KB
    __shared__ float sX[2][4][512];

    const int tid  = threadIdx.x;
    const int wave = tid >> 6;
    const int lane = tid & 63;
    const int quad = lane >> 4;
    const int l15  = lane & 15;

    // XCD-pair swizzle: the two m-halves of a (n-tile, j-window) slice are
    // consecutive on the same XCD (bid and bid+8) so the 2nd W read hits L2.
    const int bid   = blockIdx.x;
    const int xcd   = bid & 7;
    const int useq  = bid >> 3;                 // 0..63 per XCD
    const int mh    = useq & 1;
    const int slice = (useq >> 1) + (xcd << 5); // 0..255
    const int n0 = (slice & 15) << 6;           // output-col tile base (64 wide)
    const int jw = slice >> 4;                  // j-window index (0..15) = split-K id
    const int j0 = jw << 5;                     // j-window base (32 wide)
    const int m0 = mh << 9;                     // batch-row half (512 rows)

    const int mbase  = m0 + wave * 128 + l15;   // global row of subtile s: mbase + 16*s
    const int lrbase = wave * 128 + l15;        // local row within the 512-row half

    // ---- y fragments: fp32, register-resident for the whole kernel ----
    float yf[8][8];
#pragma unroll
    for (int s = 0; s < 8; ++s) {
        const float* yp = y + (size_t)(mbase + s * 16) * N2C + (j0 + quad * 8);
        f32x4 a = *(const f32x4*)yp;
        f32x4 b = *(const f32x4*)(yp + 4);
#pragma unroll
        for (int t = 0; t < 4; ++t) { yf[s][t] = a[t]; yf[s][4 + t] = b[t]; }
    }

    f32x4 acc[8][4];
#pragma unroll
    for (int s = 0; s < 8; ++s)
#pragma unroll
        for (int un = 0; un < 4; ++un)
            acc[s][un] = {0.0f, 0.0f, 0.0f, 0.0f};

    // W staging coordinates: thread -> (W row sr, 8-col group sc8)
    const int sr  = tid >> 2;
    const int sc8 = (tid & 3) * 8;
    const float* wrow = W + (size_t)(n0 + sr) * WROWC + sc8;

    // x staging coordinates: thread -> (ii, 8-row group)
    const int iix   = tid >> 6;     // 0..3
    const int lanex = tid & 63;

    // ---- prologue: stage phase 0 (linear) + phase 1 tiles ----
    stage_direct(&sB[0][0][sr][sc8], wrow + j0);
    stage_direct(&sB[0][1][sr][sc8], wrow + N1C + j0);
    {
        const int kc0 = QOFFC + j0;
#pragma unroll
        for (int ii = 0; ii < 4; ++ii)
            stage_direct(&sB[1][ii][sr][sc8], wrow + kc0 + (ii << 9));
    }
    if constexpr (USE_XT) {
        // phase 1 uses ibase = 0
        const float* xs = xT + (size_t)iix * MC + m0 + lanex * 8;
        f32x4 a = *(const f32x4*)xs;
        f32x4 b = *(const f32x4*)(xs + 4);
        *(f32x4*)&sX[1][iix][lanex * 8]     = a;
        *(f32x4*)&sX[1][iix][lanex * 8 + 4] = b;
    }
    __syncthreads();

    // ---- phase 0 compute: pseudo steps for the linear terms ----
    {
        bf16x8 afr[8];
        // ii = 0 : A = x[:, j-window]
#pragma unroll
        for (int s = 0; s < 8; ++s) {
            const float* xp = x + (size_t)(mbase + s * 16) * N1C + (j0 + quad * 8);
            f32x4 a = *(const f32x4*)xp;
            f32x4 b = *(const f32x4*)(xp + 4);
            FragU f;
            f.h2[0] = cvt2(a[0], a[1]); f.h2[1] = cvt2(a[2], a[3]);
            f.h2[2] = cvt2(b[0], b[1]); f.h2[3] = cvt2(b[2], b[3]);
            afr[s] = f.v;
        }
        {
            bf16x8 bfr[4];
#pragma unroll
            for (int un = 0; un < 4; ++un)
                bfr[un] = *(const bf16x8*)&sB[0][0][un * 16 + l15][quad * 8];
#pragma unroll
            for (int s = 0; s < 8; ++s)
#pragma unroll
                for (int un = 0; un < 4; ++un)
                    acc[s][un] = __builtin_amdgcn_mfma_f32_16x16x32_bf16(afr[s], bfr[un], acc[s][un], 0, 0, 0);
        }
        // ii = 1 : A = y[:, j-window]
#pragma unroll
        for (int s = 0; s < 8; ++s) {
            FragU f;
            f.h2[0] = cvt2(yf[s][0], yf[s][1]); f.h2[1] = cvt2(yf[s][2], yf[s][3]);
            f.h2[2] = cvt2(yf[s][4], yf[s][5]); f.h2[3] = cvt2(yf[s][6], yf[s][7]);
            afr[s] = f.v;
        }
        {
            bf16x8 bfr[4];
#pragma unroll
            for (int un = 0; un < 4; ++un)
                bfr[un] = *(const bf16x8*)&sB[0][1][un * 16 + l15][quad * 8];
#pragma unroll
            for (int s = 0; s < 8; ++s)
#pragma unroll
                for (int un = 0; un < 4; ++un)
                    acc[s][un] = __builtin_amdgcn_mfma_f32_16x16x32_bf16(afr[s], bfr[un], acc[s][un], 0, 0, 0);
        }
    }

    // ---- main loop: phases 1..128, T14 async-stage split ----
    // A: issue next-phase global loads -> regs (latency hides under B)
    // B: compute current phase from LDS
    // C: cvt + LDS-write staged regs into the other buffer
    // D: one barrier
    for (int p = 1; p < NPHASE; ++p) {
        const int cur = p & 1;
        const int nxt = cur ^ 1;
        const bool pref = (p + 1 < NPHASE);

        // ---- A: issue loads for phase p+1 ----
        f32x4 wra[4], wrb[4], xra, xrb;
        if (pref) {
            const int kc0 = QOFFC + (p << 11) + j0;   // ibase_{p+1}*512 + j0
#pragma unroll
            for (int ii = 0; ii < 4; ++ii) {
                const float* src = wrow + kc0 + (ii << 9);
                wra[ii] = *(const f32x4*)src;
                wrb[ii] = *(const f32x4*)(src + 4);
            }
            if constexpr (USE_XT) {
                const float* xs = xT + (size_t)((p << 2) + iix) * MC + m0 + lanex * 8;
                xra = *(const f32x4*)xs;
                xrb = *(const f32x4*)(xs + 4);
            }
        }

        f32x4 xq[8];
        if constexpr (!USE_XT) {
            const int ibase = (p - 1) * 4;
#pragma unroll
            for (int s = 0; s < 8; ++s)
                xq[s] = *(const f32x4*)(x + (size_t)(mbase + s * 16) * N1C + ibase);
        }

        // ---- B: compute phase p ----
#pragma unroll
        for (int ii = 0; ii < 4; ++ii) {
            bf16x8 bfr[4];
#pragma unroll
            for (int un = 0; un < 4; ++un)
                bfr[un] = *(const bf16x8*)&sB[cur][ii][un * 16 + l15][quad * 8];
#pragma unroll
            for (int s = 0; s < 8; ++s) {
                float xs_v;
                if constexpr (USE_XT) xs_v = sX[cur][ii][lrbase + s * 16];
                else                  xs_v = xq[s][ii];
                FragU f;
                f.h2[0] = cvt2(xs_v * yf[s][0], xs_v * yf[s][1]);
                f.h2[1] = cvt2(xs_v * yf[s][2], xs_v * yf[s][3]);
                f.h2[2] = cvt2(xs_v * yf[s][4], xs_v * yf[s][5]);
                f.h2[3] = cvt2(xs_v * yf[s][6], xs_v * yf[s][7]);
#pragma unroll
                for (int un = 0; un < 4; ++un)
                    acc[s][un] = __builtin_amdgcn_mfma_f32_16x16x32_bf16(f.v, bfr[un], acc[s][un], 0, 0, 0);
            }
        }

        // ---- C: write staged data for p+1 ----
        if (pref) {
#pragma unroll
            for (int ii = 0; ii < 4; ++ii) {
                FragU f;
                f.h2[0] = cvt2(wra[ii][0], wra[ii][1]); f.h2[1] = cvt2(wra[ii][2], wra[ii][3]);
                f.h2[2] = cvt2(wrb[ii][0], wrb[ii][1]); f.h2[3] = cvt2(wrb[ii][2], wrb[ii][3]);
                *(bf16x8*)&sB[nxt][ii][sr][sc8] = f.v;
            }
            if constexpr (USE_XT) {
                *(f32x4*)&sX[nxt][iix][lanex * 8]     = xra;
                *(f32x4*)&sX[nxt][iix][lanex * 8 + 4] = xrb;
            }
        }
        __syncthreads();
    }

    // ---- epilogue ----
    // C/D layout (m89/m91): col = lane&15, row = quad*4 + reg
    if constexpr (USE_WS) {
        float* dst = out + (size_t)jw * (MC * NOUTC);
#pragma unroll
        for (int s = 0; s < 8; ++s) {
            const int row0 = m0 + wave * 128 + s * 16 + quad * 4;
#pragma unroll
            for (int un = 0; un < 4; ++un) {
                const int col = n0 + un * 16 + l15;
#pragma unroll
                for (int r = 0; r < 4; ++r)
                    dst[(size_t)(row0 + r) * NOUTC + col] = acc[s][un][r];
            }
        }
    } else {
#pragma unroll
        for (int s = 0; s < 8; ++s) {
            const int row0 = m0 + wave * 128 + s * 16 + quad * 4;
#pragma unroll
            for (int un = 0; un < 4; ++un) {
                const int col = n0 + un * 16 + l15;
#pragma unroll
                for (int r = 0; r < 4; ++r)
                    atomicAdd(out + (size_t)(row0 + r) * NOUTC + col, acc[s][un][r]);
            }
        }
    }
}

extern "C" void kernel_launch(void* const* d_in, const int* in_sizes, int n_in,
                              void* d_out, int out_size, void* d_ws, size_t ws_size,
                              hipStream_t stream) {
    const float* x = (const float*)d_in[0];
    const float* y = (const float*)d_in[1];
    const float* W = (const float*)d_in[2];
    float* out = (float*)d_out;

    const size_t XT_BYTES   = (size_t)N1C * MC * sizeof(float);             // 2 MB
    const size_t PART_BYTES = (size_t)NSPLIT * MC * NOUTC * sizeof(float);  // 64 MB
    const bool haveXT = ws_size >= XT_BYTES;
    const bool haveWS = ws_size >= XT_BYTES + PART_BYTES;

    float* xT   = (float*)d_ws;
    float* part = (float*)((char*)d_ws + XT_BYTES);

    if (haveXT)
        transpose_x<<<dim3(N1C / 64, MC / 64), dim3(256), 0, stream>>>(x, xT);

    if (haveWS) {
        quad_gemm<true, true><<<dim3(512), dim3(256), 0, stream>>>(x, y, W, xT, part);
        reduce_parts<<<dim3((MC * NOUTC) / (256 * 4)), dim3(256), 0, stream>>>(part, out);
    } else {
        (void)hipMemsetAsync(out, 0, (size_t)out_size * sizeof(float), stream);
        if (haveXT)
            quad_gemm<true, false><<<dim3(512), dim3(256), 0, stream>>>(x, y, W, xT, out);
        else
            quad_gemm<false, false><<<dim3(512), dim3(256), 0, stream>>>(x, y, W, nullptr, out);
    }
}

// Round 2
// 2033.863 us; speedup vs baseline: 2.0603x; 1.1141x over previous
//
#include <hip/hip_runtime.h>
#include <hip/hip_bf16.h>

// Problem constants
#define N1C   512
#define N2C   512
#define MC    1024
#define NOUTC 1024
#define WROWC 263168      // N1*N2 + N1 + N2
#define QOFFC 1024        // start of quadratic block in a W row
#define NPHASE 129        // phase 0: linear x/y; phases 1..128: 4 i-chunks each
#define NSPLIT 16         // split-K factor (j-windows)

typedef __attribute__((ext_vector_type(8))) short bf16x8;
typedef __attribute__((ext_vector_type(4))) short bf16x4;
typedef __attribute__((ext_vector_type(4))) float f32x4;

union FragU  { bf16x8 v; __hip_bfloat162 h2[4]; };
union Frag4U { bf16x4 v; __hip_bfloat162 h2[2]; };

static __device__ __forceinline__ __hip_bfloat162 cvt2(float a, float b) {
    return __float22bfloat162_rn(make_float2(a, b));
}

// stage 4 fp32 -> 4 bf16 (8 B) into LDS
static __device__ __forceinline__ void stage4(short* dst, const float* src) {
    f32x4 a = *(const f32x4*)src;
    Frag4U f;
    f.h2[0] = cvt2(a[0], a[1]);
    f.h2[1] = cvt2(a[2], a[3]);
    *(bf16x4*)dst = f.v;
}

// ---------------- x transpose: x[1024][512] -> xT[512][1024] ----------------
__global__ __launch_bounds__(256) void transpose_x(const float* __restrict__ x,
                                                   float* __restrict__ xT) {
    __shared__ float t[64][65];
    const int i0 = blockIdx.x * 64;
    const int m0 = blockIdx.y * 64;
    const int tx = threadIdx.x & 63;
    const int ty = threadIdx.x >> 6;
#pragma unroll
    for (int k = 0; k < 16; ++k)
        t[ty * 16 + k][tx] = x[(size_t)(m0 + ty * 16 + k) * N1C + i0 + tx];
    __syncthreads();
#pragma unroll
    for (int k = 0; k < 16; ++k)
        xT[(size_t)(i0 + ty * 16 + k) * MC + m0 + tx] = t[tx][ty * 16 + k];
}

// ---------------- split-K reduction: out = sum_j part[j] ----------------
__global__ __launch_bounds__(256) void reduce_parts(const float* __restrict__ part,
                                                    float* __restrict__ out) {
    const size_t idx = ((size_t)blockIdx.x * 256 + threadIdx.x) * 4;
    f32x4 s = *(const f32x4*)(part + idx);
#pragma unroll
    for (int j = 1; j < NSPLIT; ++j)
        s += *(const f32x4*)(part + (size_t)j * (MC * NOUTC) + idx);
    *(f32x4*)(out + idx) = s;
}

// ---------------- main kernel ----------------
// Block: 512 threads (8 waves), tile = 256 rows x 64 cols x 32-j window.
// Wave (wm 0..3, wn 0..1): 64 rows x 32 cols -> acc[4][2] (32 regs).
// Grid: 4 m-quarters x 16 n-tiles x 16 j-windows = 1024 blocks, 2/CU.
template<bool USE_XT, bool USE_WS>
__global__ __launch_bounds__(512, 4) void quad_gemm(
        const float* __restrict__ x, const float* __restrict__ y,
        const float* __restrict__ W, const float* __restrict__ xT,
        float* __restrict__ out)
{
    // W tiles: [buf][ii][n-row][j + pad] : 2*4*64*40*2B = 40 KB exactly
    __shared__ short sB[2][4][64][40];

    const int tid  = threadIdx.x;
    const int wave = tid >> 6;
    const int wm   = wave >> 1;     // 0..3 : 64-row group
    const int wn   = wave & 1;      // 0..1 : 32-col half
    const int lane = tid & 63;
    const int quad = lane >> 4;
    const int l15  = lane & 15;

    // XCD swizzle: the 4 m-quarters of one (n-tile, j-window) slice are bids
    // {b, b+8, b+16, b+24} -> same XCD, co-resident -> W re-reads hit L2.
    const int bid   = blockIdx.x;
    const int xcd   = bid & 7;
    const int useq  = bid >> 3;                 // 0..127 per XCD
    const int mq    = useq & 3;                 // m-quarter
    const int slice = (useq >> 2) + (xcd << 5); // 0..255
    const int n0 = (slice & 15) << 6;           // output-col tile base (64)
    const int jw = slice >> 4;                  // j-window = split-K id
    const int j0 = jw << 5;
    const int m0 = mq << 8;                     // 256-row quarter base

    const int mbase = m0 + wm * 64 + l15;       // row of subtile s: mbase + 16*s
    const int nb    = wn * 32;                  // col offset of this wave's half

    // ---- y fragments: fp32, register-resident for the whole kernel ----
    float yf[4][8];
#pragma unroll
    for (int s = 0; s < 4; ++s) {
        const float* yp = y + (size_t)(mbase + s * 16) * N2C + (j0 + quad * 8);
        f32x4 a = *(const f32x4*)yp;
        f32x4 b = *(const f32x4*)(yp + 4);
#pragma unroll
        for (int t = 0; t < 4; ++t) { yf[s][t] = a[t]; yf[s][4 + t] = b[t]; }
    }

    f32x4 acc[4][2];
#pragma unroll
    for (int s = 0; s < 4; ++s)
#pragma unroll
        for (int un = 0; un < 2; ++un)
            acc[s][un] = {0.0f, 0.0f, 0.0f, 0.0f};

    // W staging: 512 threads cover 64 rows x 32 cols per ii (4 floats/thread)
    const int sr  = tid >> 3;           // 0..63
    const int sc4 = (tid & 7) << 2;     // 0,4,...,28
    const float* wrow = W + (size_t)(n0 + sr) * WROWC + sc4;

    // ---- prologue: stage phase 0 (linear) + phase 1 tiles ----
    stage4(&sB[0][0][sr][sc4], wrow + j0);
    stage4(&sB[0][1][sr][sc4], wrow + N1C + j0);
#pragma unroll
    for (int ii = 0; ii < 4; ++ii)
        stage4(&sB[1][ii][sr][sc4], wrow + QOFFC + j0 + (ii << 9));
    __syncthreads();

    // ---- phase 0 compute: linear terms ----
    {
        bf16x8 bfr[2];
        // ii = 0 : A = x[:, j-window]
#pragma unroll
        for (int un = 0; un < 2; ++un)
            bfr[un] = *(const bf16x8*)&sB[0][0][nb + un * 16 + l15][quad * 8];
#pragma unroll
        for (int s = 0; s < 4; ++s) {
            const float* xp = x + (size_t)(mbase + s * 16) * N1C + (j0 + quad * 8);
            f32x4 a = *(const f32x4*)xp;
            f32x4 b = *(const f32x4*)(xp + 4);
            FragU f;
            f.h2[0] = cvt2(a[0], a[1]); f.h2[1] = cvt2(a[2], a[3]);
            f.h2[2] = cvt2(b[0], b[1]); f.h2[3] = cvt2(b[2], b[3]);
#pragma unroll
            for (int un = 0; un < 2; ++un)
                acc[s][un] = __builtin_amdgcn_mfma_f32_16x16x32_bf16(f.v, bfr[un], acc[s][un], 0, 0, 0);
        }
        // ii = 1 : A = y[:, j-window]
#pragma unroll
        for (int un = 0; un < 2; ++un)
            bfr[un] = *(const bf16x8*)&sB[0][1][nb + un * 16 + l15][quad * 8];
#pragma unroll
        for (int s = 0; s < 4; ++s) {
            FragU f;
            f.h2[0] = cvt2(yf[s][0], yf[s][1]); f.h2[1] = cvt2(yf[s][2], yf[s][3]);
            f.h2[2] = cvt2(yf[s][4], yf[s][5]); f.h2[3] = cvt2(yf[s][6], yf[s][7]);
#pragma unroll
            for (int un = 0; un < 2; ++un)
                acc[s][un] = __builtin_amdgcn_mfma_f32_16x16x32_bf16(f.v, bfr[un], acc[s][un], 0, 0, 0);
        }
    }

    // ---- main loop: phases 1..128 ----
    for (int p = 1; p < NPHASE; ++p) {
        const int cur = p & 1;
        const int nxt = cur ^ 1;
        const bool pref = (p + 1 < NPHASE);

        // x values for this phase (L2-hot 16 KB slice shared by all blocks)
        float xq[4][4];
        if constexpr (USE_XT) {
            const int ibase = (p - 1) << 2;
#pragma unroll
            for (int ii = 0; ii < 4; ++ii)
#pragma unroll
                for (int s = 0; s < 4; ++s)
                    xq[s][ii] = xT[(size_t)(ibase + ii) * MC + mbase + s * 16];
        } else {
            const int ibase = (p - 1) << 2;
#pragma unroll
            for (int s = 0; s < 4; ++s) {
                f32x4 t = *(const f32x4*)(x + (size_t)(mbase + s * 16) * N1C + ibase);
#pragma unroll
                for (int ii = 0; ii < 4; ++ii) xq[s][ii] = t[ii];
            }
        }

        // T14: issue next-phase W loads (4 x dwordx4), consumed after compute
        f32x4 wr[4];
        if (pref) {
            const int kc0 = QOFFC + (p << 11) + j0;   // (p*4)*512 + j0
#pragma unroll
            for (int ii = 0; ii < 4; ++ii)
                wr[ii] = *(const f32x4*)(wrow + kc0 + (ii << 9));
        }

        // compute phase p
#pragma unroll
        for (int ii = 0; ii < 4; ++ii) {
            bf16x8 bfr[2];
#pragma unroll
            for (int un = 0; un < 2; ++un)
                bfr[un] = *(const bf16x8*)&sB[cur][ii][nb + un * 16 + l15][quad * 8];
#pragma unroll
            for (int s = 0; s < 4; ++s) {
                const float xs = xq[s][ii];
                FragU f;
                f.h2[0] = cvt2(xs * yf[s][0], xs * yf[s][1]);
                f.h2[1] = cvt2(xs * yf[s][2], xs * yf[s][3]);
                f.h2[2] = cvt2(xs * yf[s][4], xs * yf[s][5]);
                f.h2[3] = cvt2(xs * yf[s][6], xs * yf[s][7]);
#pragma unroll
                for (int un = 0; un < 2; ++un)
                    acc[s][un] = __builtin_amdgcn_mfma_f32_16x16x32_bf16(f.v, bfr[un], acc[s][un], 0, 0, 0);
            }
        }

        // write staged W for p+1
        if (pref) {
#pragma unroll
            for (int ii = 0; ii < 4; ++ii) {
                Frag4U f;
                f.h2[0] = cvt2(wr[ii][0], wr[ii][1]);
                f.h2[1] = cvt2(wr[ii][2], wr[ii][3]);
                *(bf16x4*)&sB[nxt][ii][sr][sc4] = f.v;
            }
        }
        __syncthreads();
    }

    // ---- epilogue ----
    // C/D layout (m89/m91): col = lane&15, row = quad*4 + reg
    if constexpr (USE_WS) {
        float* dst = out + (size_t)jw * (MC * NOUTC);
#pragma unroll
        for (int s = 0; s < 4; ++s) {
            const int row0 = m0 + wm * 64 + s * 16 + quad * 4;
#pragma unroll
            for (int un = 0; un < 2; ++un) {
                const int col = n0 + nb + un * 16 + l15;
#pragma unroll
                for (int r = 0; r < 4; ++r)
                    dst[(size_t)(row0 + r) * NOUTC + col] = acc[s][un][r];
            }
        }
    } else {
#pragma unroll
        for (int s = 0; s < 4; ++s) {
            const int row0 = m0 + wm * 64 + s * 16 + quad * 4;
#pragma unroll
            for (int un = 0; un < 2; ++un) {
                const int col = n0 + nb + un * 16 + l15;
#pragma unroll
                for (int r = 0; r < 4; ++r)
                    atomicAdd(out + (size_t)(row0 + r) * NOUTC + col, acc[s][un][r]);
            }
        }
    }
}

extern "C" void kernel_launch(void* const* d_in, const int* in_sizes, int n_in,
                              void* d_out, int out_size, void* d_ws, size_t ws_size,
                              hipStream_t stream) {
    const float* x = (const float*)d_in[0];
    const float* y = (const float*)d_in[1];
    const float* W = (const float*)d_in[2];
    float* out = (float*)d_out;

    const size_t XT_BYTES   = (size_t)N1C * MC * sizeof(float);             // 2 MB
    const size_t PART_BYTES = (size_t)NSPLIT * MC * NOUTC * sizeof(float);  // 64 MB
    const bool haveXT = ws_size >= XT_BYTES;
    const bool haveWS = ws_size >= XT_BYTES + PART_BYTES;

    float* xT   = (float*)d_ws;
    float* part = (float*)((char*)d_ws + XT_BYTES);

    if (haveXT)
        transpose_x<<<dim3(N1C / 64, MC / 64), dim3(256), 0, stream>>>(x, xT);

    if (haveWS) {
        quad_gemm<true, true><<<dim3(1024), dim3(512), 0, stream>>>(x, y, W, xT, part);
        reduce_parts<<<dim3((MC * NOUTC) / (256 * 4)), dim3(256), 0, stream>>>(part, out);
    } else {
        (void)hipMemsetAsync(out, 0, (size_t)out_size * sizeof(float), stream);
        if (haveXT)
            quad_gemm<true, false><<<dim3(1024), dim3(512), 0, stream>>>(x, y, W, xT, out);
        else
            quad_gemm<false, false><<<dim3(1024), dim3(512), 0, stream>>>(x, y, W, nullptr, out);
    }
}